// Round 2
// baseline (129.788 us; speedup 1.0000x reference)
//
#include <hip/hip_runtime.h>

#define NROWS 8192
#define NSPLIT 8
#define JT (NROWS / NSPLIT)  // 1024 j's per split
#define L2E 1.4426950408889634f
// -9e15 * log2(e), so that exp2() in scaled domain == exp() in original domain
#define MASKVAL -1.2984255368000352e16f

typedef __attribute__((ext_vector_type(4))) float f32x4;
typedef __attribute__((ext_vector_type(8))) __bf16 bf16x8;
typedef __attribute__((ext_vector_type(4))) unsigned int u32x4;

__device__ __forceinline__ unsigned short f2bf(float x) {
  unsigned u = __float_as_uint(x);
  u += 0x7fffu + ((u >> 16) & 1u);
  return (unsigned short)(u >> 16);
}

// ---------------------------------------------------------------------------
// Kernel A: Wh = h@W (stored bf16 in MFMA-B-fragment order), src=Wh@a1, dst=Wh@a2
// src/dst pre-scaled by log2(e) so k_attn works in exp2 domain.
// One wave per row; lane = output feature.
// Fragment layout: slot (jc, nt, lane, e) holds Wh[j = 32*jc + 8*(lane>>4) + e][nt*16 + (lane&15)]
// ---------------------------------------------------------------------------
__global__ __launch_bounds__(256) void k_prep(
    const float* __restrict__ h, const float* __restrict__ W,
    const float* __restrict__ a, unsigned short* __restrict__ WhB,
    float* __restrict__ src, float* __restrict__ dst) {
  int i = blockIdx.x * 4 + (threadIdx.x >> 6);  // row
  int lane = threadIdx.x & 63;                  // feature
  const float* hrow = h + (size_t)i * 256;
  float s = 0.f;
#pragma unroll 4
  for (int k = 0; k < 256; k += 4) {
    float4 hv = *(const float4*)(hrow + k);
    s = fmaf(hv.x, W[(k + 0) * 64 + lane], s);
    s = fmaf(hv.y, W[(k + 1) * 64 + lane], s);
    s = fmaf(hv.z, W[(k + 2) * 64 + lane], s);
    s = fmaf(hv.w, W[(k + 3) * 64 + lane], s);
  }
  // scatter into B-fragment layout (j = i here)
  int nt = lane >> 4, c = lane & 15;
  int gi = (i >> 3) & 3, e = i & 7;
  int idx = ((((i >> 5) * 4 + nt) * 64) + c + 16 * gi) * 8 + e;
  WhB[idx] = f2bf(s);
  // src/dst reductions (scaled into exp2 domain)
  float v1 = s * a[lane];
  float v2 = s * a[64 + lane];
#pragma unroll
  for (int d = 32; d; d >>= 1) {
    v1 += __shfl_xor(v1, d);
    v2 += __shfl_xor(v2, d);
  }
  if (lane == 0) {
    src[i] = v1 * L2E;
    dst[i] = v2 * L2E;
  }
}

// ---------------------------------------------------------------------------
// Kernel B: fused masked-softmax + PV, split along j into NSPLIT partials.
// One wave = one (16-row M-tile, split) task. Online softmax (exp2 domain).
// adj loads are software-prefetched one iteration ahead.
// ---------------------------------------------------------------------------
__global__ __launch_bounds__(256, 4) void k_attn(
    const int* __restrict__ adj, const unsigned short* __restrict__ WhB,
    const float* __restrict__ src, const float* __restrict__ dst,
    float* __restrict__ pm, float* __restrict__ pl, float* __restrict__ pacc) {
  int task = blockIdx.x * 4 + (threadIdx.x >> 6);  // 0 .. 512*NSPLIT-1
  int sp = task >> 9;                              // split index
  int mt = task & 511;                             // M-tile index
  int lane = threadIdx.x & 63;
  int r = lane & 15;   // A-operand row within tile / C col
  int g = lane >> 4;   // k-slot group
  int row0 = mt * 16;
  float srcr = src[row0 + r];
  float m = -INFINITY;
  float lrow = 0.f;
  f32x4 acc[4] = {f32x4{0.f, 0.f, 0.f, 0.f}, f32x4{0.f, 0.f, 0.f, 0.f},
                  f32x4{0.f, 0.f, 0.f, 0.f}, f32x4{0.f, 0.f, 0.f, 0.f}};
  int jbase = sp * JT;
  const int* adjp = adj + (size_t)(row0 + r) * NROWS + jbase + 8 * g;
  const float* dstp = dst + jbase + 8 * g;
  const bf16x8* Bfr = (const bf16x8*)WhB;

  // prefetch registers: current adj block
  int4 ca0 = *(const int4*)(adjp + 0);
  int4 ca1 = *(const int4*)(adjp + 4);
  int4 ca2 = *(const int4*)(adjp + 32);
  int4 ca3 = *(const int4*)(adjp + 36);

  for (int jb = 0; jb < JT; jb += 64) {
    // issue next iteration's adj loads NOW (consumed next iter) — T14
    int off = (jb + 64 < JT) ? (jb + 64) : 0;  // clamp: harmless in-range reload on last iter
    int4 na0 = *(const int4*)(adjp + off);
    int4 na1 = *(const int4*)(adjp + off + 4);
    int4 na2 = *(const int4*)(adjp + off + 32);
    int4 na3 = *(const int4*)(adjp + off + 36);

    float4 d0 = *(const float4*)(dstp + jb);
    float4 d1 = *(const float4*)(dstp + jb + 4);
    float4 d2 = *(const float4*)(dstp + jb + 32);
    float4 d3 = *(const float4*)(dstp + jb + 36);

    float ev[16];
#define EC(aa, dd)                        \
  ({                                      \
    float v_ = srcr + (dd);               \
    v_ = fmaxf(v_, 0.2f * v_);            \
    ((aa) > 0) ? v_ : MASKVAL;            \
  })
    ev[0] = EC(ca0.x, d0.x);  ev[1] = EC(ca0.y, d0.y);
    ev[2] = EC(ca0.z, d0.z);  ev[3] = EC(ca0.w, d0.w);
    ev[4] = EC(ca1.x, d1.x);  ev[5] = EC(ca1.y, d1.y);
    ev[6] = EC(ca1.z, d1.z);  ev[7] = EC(ca1.w, d1.w);
    ev[8] = EC(ca2.x, d2.x);  ev[9] = EC(ca2.y, d2.y);
    ev[10] = EC(ca2.z, d2.z); ev[11] = EC(ca2.w, d2.w);
    ev[12] = EC(ca3.x, d3.x); ev[13] = EC(ca3.y, d3.y);
    ev[14] = EC(ca3.z, d3.z); ev[15] = EC(ca3.w, d3.w);
#undef EC

    float cm = ev[0];
#pragma unroll
    for (int t = 1; t < 16; t++) cm = fmaxf(cm, ev[t]);
    cm = fmaxf(cm, __shfl_xor(cm, 16));
    cm = fmaxf(cm, __shfl_xor(cm, 32));
    float mnew = fmaxf(m, cm);

    // exp2 + pack to bf16 pairs (v_cvt_pk_bf16_f32)
    float ps = 0.f;
    unsigned q[8];
#pragma unroll
    for (int t = 0; t < 16; t += 2) {
      float p0 = exp2f(ev[t] - mnew);
      float p1 = exp2f(ev[t + 1] - mnew);
      ps += p0 + p1;
      unsigned qq;
      asm("v_cvt_pk_bf16_f32 %0, %1, %2" : "=v"(qq) : "v"(p0), "v"(p1));
      q[t >> 1] = qq;
    }
    ps += __shfl_xor(ps, 16);
    ps += __shfl_xor(ps, 32);

    if (__any(mnew > m)) {
      float sc = exp2f(m - mnew);  // this lane's row (r) scale
      float s0 = __shfl(sc, 4 * g + 0);
      float s1 = __shfl(sc, 4 * g + 1);
      float s2 = __shfl(sc, 4 * g + 2);
      float s3 = __shfl(sc, 4 * g + 3);
#pragma unroll
      for (int nt = 0; nt < 4; nt++) {
        acc[nt][0] *= s0;
        acc[nt][1] *= s1;
        acc[nt][2] *= s2;
        acc[nt][3] *= s3;
      }
      lrow = lrow * sc + ps;
    } else {
      lrow += ps;
    }
    m = mnew;

    u32x4 qv0 = {q[0], q[1], q[2], q[3]};
    u32x4 qv1 = {q[4], q[5], q[6], q[7]};
    bf16x8 A0 = __builtin_bit_cast(bf16x8, qv0);
    bf16x8 A1 = __builtin_bit_cast(bf16x8, qv1);
    int jc = (jbase + jb) >> 5;
    __builtin_amdgcn_s_setprio(1);
#pragma unroll
    for (int nt = 0; nt < 4; nt++) {
      bf16x8 B0 = Bfr[((jc) * 4 + nt) * 64 + lane];
      bf16x8 B1 = Bfr[((jc + 1) * 4 + nt) * 64 + lane];
      acc[nt] = __builtin_amdgcn_mfma_f32_16x16x32_bf16(A0, B0, acc[nt], 0, 0, 0);
      acc[nt] = __builtin_amdgcn_mfma_f32_16x16x32_bf16(A1, B1, acc[nt], 0, 0, 0);
    }
    __builtin_amdgcn_s_setprio(0);

    ca0 = na0; ca1 = na1; ca2 = na2; ca3 = na3;
  }

  if (lane < 16) {
    pm[sp * NROWS + row0 + lane] = m;
    pl[sp * NROWS + row0 + lane] = lrow;
  }
#pragma unroll
  for (int nt = 0; nt < 4; nt++)
#pragma unroll
    for (int q2 = 0; q2 < 4; q2++)
      pacc[((size_t)sp * NROWS + row0 + 4 * g + q2) * 64 + nt * 16 + r] = acc[nt][q2];
}

// ---------------------------------------------------------------------------
// Kernel C: combine split partials. One thread per output element. (exp2 domain)
// ---------------------------------------------------------------------------
__global__ __launch_bounds__(256) void k_comb(
    const float* __restrict__ pm, const float* __restrict__ pl,
    const float* __restrict__ pacc, float* __restrict__ out) {
  int t = blockIdx.x * 256 + threadIdx.x;
  int row = t >> 6, f = t & 63;
  float mv[NSPLIT];
  float M = -INFINITY;
#pragma unroll
  for (int s2 = 0; s2 < NSPLIT; s2++) {
    mv[s2] = pm[s2 * NROWS + row];
    M = fmaxf(M, mv[s2]);
  }
  float L = 0.f, o = 0.f;
#pragma unroll
  for (int s2 = 0; s2 < NSPLIT; s2++) {
    float w = exp2f(mv[s2] - M);
    L += pl[s2 * NROWS + row] * w;
    o += pacc[((size_t)s2 * NROWS + row) * 64 + f] * w;
  }
  out[t] = o / L;
}

extern "C" void kernel_launch(void* const* d_in, const int* in_sizes, int n_in,
                              void* d_out, int out_size, void* d_ws, size_t ws_size,
                              hipStream_t stream) {
  const float* h = (const float*)d_in[0];
  const float* W = (const float*)d_in[1];
  const float* a = (const float*)d_in[2];
  const int* adj = (const int*)d_in[3];
  float* out = (float*)d_out;

  char* ws = (char*)d_ws;
  unsigned short* WhB = (unsigned short*)ws;                     // 1 MB
  float* src = (float*)(ws + (1 << 20));                         // 32 KB
  float* dst = (float*)(ws + (1 << 20) + 32768);                 // 32 KB
  float* pm = (float*)(ws + (1 << 20) + 65536);                  // 256 KB
  float* pl = (float*)(ws + (1 << 20) + 65536 + NSPLIT * NROWS * 4);
  float* pacc = (float*)(ws + (1 << 20) + 65536 + 2 * NSPLIT * NROWS * 4);  // 16 MB

  hipLaunchKernelGGL(k_prep, dim3(NROWS / 4), dim3(256), 0, stream, h, W, a, WhB, src, dst);
  hipLaunchKernelGGL(k_attn, dim3(512 * NSPLIT / 4), dim3(256), 0, stream,
                     adj, WhB, src, dst, pm, pl, pacc);
  hipLaunchKernelGGL(k_comb, dim3(NROWS * 64 / 256), dim3(256), 0, stream, pm, pl, pacc, out);
}

// Round 3
// 123.281 us; speedup vs baseline: 1.0528x; 1.0528x over previous
//
#include <hip/hip_runtime.h>

#define NROWS 8192
#define NSPLIT 8
#define JT (NROWS / NSPLIT)  // 1024 j's per split
#define L2E 1.4426950408889634f
// -9e15 * log2(e), so that exp2() in scaled domain == exp() in original domain
#define MASKVAL -1.2984255368000352e16f

typedef __attribute__((ext_vector_type(4))) float f32x4;
typedef __attribute__((ext_vector_type(8))) __bf16 bf16x8;
typedef __attribute__((ext_vector_type(4))) unsigned int u32x4;

__device__ __forceinline__ unsigned short f2bf(float x) {
  unsigned u = __float_as_uint(x);
  u += 0x7fffu + ((u >> 16) & 1u);
  return (unsigned short)(u >> 16);
}

// ---------------------------------------------------------------------------
// Kernel A: Wh = h@W (stored bf16 in MFMA-B-fragment order), src=Wh@a1, dst=Wh@a2
// src/dst pre-scaled by log2(e) so k_attn works in exp2 domain.
// Fragment layout: slot (jc, nt, lane, e) holds Wh[j = 32*jc + 8*(lane>>4) + e][nt*16 + (lane&15)]
// ---------------------------------------------------------------------------
__global__ __launch_bounds__(256) void k_prep(
    const float* __restrict__ h, const float* __restrict__ W,
    const float* __restrict__ a, unsigned short* __restrict__ WhB,
    float* __restrict__ src, float* __restrict__ dst) {
  int i = blockIdx.x * 4 + (threadIdx.x >> 6);  // row
  int lane = threadIdx.x & 63;                  // feature
  const float* hrow = h + (size_t)i * 256;
  float s = 0.f;
#pragma unroll 4
  for (int k = 0; k < 256; k += 4) {
    float4 hv = *(const float4*)(hrow + k);
    s = fmaf(hv.x, W[(k + 0) * 64 + lane], s);
    s = fmaf(hv.y, W[(k + 1) * 64 + lane], s);
    s = fmaf(hv.z, W[(k + 2) * 64 + lane], s);
    s = fmaf(hv.w, W[(k + 3) * 64 + lane], s);
  }
  int nt = lane >> 4, c = lane & 15;
  int gi = (i >> 3) & 3, e = i & 7;
  int idx = ((((i >> 5) * 4 + nt) * 64) + c + 16 * gi) * 8 + e;
  WhB[idx] = f2bf(s);
  float v1 = s * a[lane];
  float v2 = s * a[64 + lane];
#pragma unroll
  for (int d = 32; d; d >>= 1) {
    v1 += __shfl_xor(v1, d);
    v2 += __shfl_xor(v2, d);
  }
  if (lane == 0) {
    src[i] = v1 * L2E;
    dst[i] = v2 * L2E;
  }
}

// ---------------------------------------------------------------------------
// Kernel B: fused masked-softmax + PV, split along j into NSPLIT partials.
// One wave = one (16-row M-tile, split) task. Online softmax (exp2 domain).
// Issue order == consumption order so counted vmcnt waits never drain the
// adj prefetch (vmcnt retires in order):
//   per iter t: [dst(t)] [B(t)] [adj(t+1)] | EC(adj(t),dst(t)) | MFMA(B(t))
// ---------------------------------------------------------------------------
__global__ __launch_bounds__(256, 4) void k_attn(
    const int* __restrict__ adj, const unsigned short* __restrict__ WhB,
    const float* __restrict__ src, const float* __restrict__ dst,
    float* __restrict__ pm, float* __restrict__ pl, float* __restrict__ pacc) {
  int task = blockIdx.x * 4 + (threadIdx.x >> 6);  // 0 .. 512*NSPLIT-1
  int sp = task >> 9;                              // split index
  int mt = task & 511;                             // M-tile index
  int lane = threadIdx.x & 63;
  int r = lane & 15;   // A-operand row within tile / C col
  int g = lane >> 4;   // k-slot group
  int row0 = mt * 16;
  float srcr = src[row0 + r];
  float m = -INFINITY;
  float lrow = 0.f;
  f32x4 acc[4] = {f32x4{0.f, 0.f, 0.f, 0.f}, f32x4{0.f, 0.f, 0.f, 0.f},
                  f32x4{0.f, 0.f, 0.f, 0.f}, f32x4{0.f, 0.f, 0.f, 0.f}};
  int jbase = sp * JT;
  const int* adjp = adj + (size_t)(row0 + r) * NROWS + jbase + 8 * g;
  const float* dstp = dst + jbase + 8 * g;
  const bf16x8* Bfr = (const bf16x8*)WhB;

  // prologue: adj(0) in flight
  int4 ca0 = *(const int4*)(adjp + 0);
  int4 ca1 = *(const int4*)(adjp + 4);
  int4 ca2 = *(const int4*)(adjp + 32);
  int4 ca3 = *(const int4*)(adjp + 36);

  for (int jb = 0; jb < JT; jb += 64) {
    // --- 1. dst(t): L2-hot, issued first so its wait never drains adj(t+1)
    float4 d0 = *(const float4*)(dstp + jb);
    float4 d1 = *(const float4*)(dstp + jb + 4);
    float4 d2 = *(const float4*)(dstp + jb + 32);
    float4 d3 = *(const float4*)(dstp + jb + 36);

    // --- 2. B(t): L2-hot fragment loads, consumed at MFMA below
    int jc = (jbase + jb) >> 5;
    const bf16x8* bp = Bfr + (size_t)jc * 256 + lane;
    bf16x8 b0 = bp[0];
    bf16x8 b1 = bp[64];
    bf16x8 b2 = bp[128];
    bf16x8 b3 = bp[192];
    bf16x8 b4 = bp[256];
    bf16x8 b5 = bp[320];
    bf16x8 b6 = bp[384];
    bf16x8 b7 = bp[448];
    __builtin_amdgcn_sched_barrier(0);

    // --- 3. adj(t+1) prefetch: HBM, stays in flight across the whole compute
    int off = (jb + 64 < JT) ? (jb + 64) : 0;  // clamped reload on last iter
    int4 na0 = *(const int4*)(adjp + off);
    int4 na1 = *(const int4*)(adjp + off + 4);
    int4 na2 = *(const int4*)(adjp + off + 32);
    int4 na3 = *(const int4*)(adjp + off + 36);
    __builtin_amdgcn_sched_barrier(0);

    // --- 4. scores from adj(t) + dst(t)
    float ev[16];
#define EC(aa, dd)                        \
  ({                                      \
    float v_ = srcr + (dd);               \
    v_ = fmaxf(v_, 0.2f * v_);            \
    ((aa) > 0) ? v_ : MASKVAL;            \
  })
    ev[0] = EC(ca0.x, d0.x);  ev[1] = EC(ca0.y, d0.y);
    ev[2] = EC(ca0.z, d0.z);  ev[3] = EC(ca0.w, d0.w);
    ev[4] = EC(ca1.x, d1.x);  ev[5] = EC(ca1.y, d1.y);
    ev[6] = EC(ca1.z, d1.z);  ev[7] = EC(ca1.w, d1.w);
    ev[8] = EC(ca2.x, d2.x);  ev[9] = EC(ca2.y, d2.y);
    ev[10] = EC(ca2.z, d2.z); ev[11] = EC(ca2.w, d2.w);
    ev[12] = EC(ca3.x, d3.x); ev[13] = EC(ca3.y, d3.y);
    ev[14] = EC(ca3.z, d3.z); ev[15] = EC(ca3.w, d3.w);
#undef EC

    float cm = ev[0];
#pragma unroll
    for (int t = 1; t < 16; t++) cm = fmaxf(cm, ev[t]);
    cm = fmaxf(cm, __shfl_xor(cm, 16));
    cm = fmaxf(cm, __shfl_xor(cm, 32));
    float mnew = fmaxf(m, cm);

    float ps = 0.f;
    unsigned q[8];
#pragma unroll
    for (int t = 0; t < 16; t += 2) {
      float p0 = exp2f(ev[t] - mnew);
      float p1 = exp2f(ev[t + 1] - mnew);
      ps += p0 + p1;
      unsigned qq;
      asm("v_cvt_pk_bf16_f32 %0, %1, %2" : "=v"(qq) : "v"(p0), "v"(p1));
      q[t >> 1] = qq;
    }
    ps += __shfl_xor(ps, 16);
    ps += __shfl_xor(ps, 32);

    if (__any(mnew > m)) {
      float sc = exp2f(m - mnew);  // this lane's row (r) scale
      float s0 = __shfl(sc, 4 * g + 0);
      float s1 = __shfl(sc, 4 * g + 1);
      float s2 = __shfl(sc, 4 * g + 2);
      float s3 = __shfl(sc, 4 * g + 3);
#pragma unroll
      for (int nt = 0; nt < 4; nt++) {
        acc[nt][0] *= s0;
        acc[nt][1] *= s1;
        acc[nt][2] *= s2;
        acc[nt][3] *= s3;
      }
      lrow = lrow * sc + ps;
    } else {
      lrow += ps;
    }
    m = mnew;

    u32x4 qv0 = {q[0], q[1], q[2], q[3]};
    u32x4 qv1 = {q[4], q[5], q[6], q[7]};
    bf16x8 A0 = __builtin_bit_cast(bf16x8, qv0);
    bf16x8 A1 = __builtin_bit_cast(bf16x8, qv1);

    // --- 5. MFMA consumes B(t); counted wait leaves adj(t+1) in flight
    __builtin_amdgcn_s_setprio(1);
    acc[0] = __builtin_amdgcn_mfma_f32_16x16x32_bf16(A0, b0, acc[0], 0, 0, 0);
    acc[1] = __builtin_amdgcn_mfma_f32_16x16x32_bf16(A0, b1, acc[1], 0, 0, 0);
    acc[2] = __builtin_amdgcn_mfma_f32_16x16x32_bf16(A0, b2, acc[2], 0, 0, 0);
    acc[3] = __builtin_amdgcn_mfma_f32_16x16x32_bf16(A0, b3, acc[3], 0, 0, 0);
    acc[0] = __builtin_amdgcn_mfma_f32_16x16x32_bf16(A1, b4, acc[0], 0, 0, 0);
    acc[1] = __builtin_amdgcn_mfma_f32_16x16x32_bf16(A1, b5, acc[1], 0, 0, 0);
    acc[2] = __builtin_amdgcn_mfma_f32_16x16x32_bf16(A1, b6, acc[2], 0, 0, 0);
    acc[3] = __builtin_amdgcn_mfma_f32_16x16x32_bf16(A1, b7, acc[3], 0, 0, 0);
    __builtin_amdgcn_s_setprio(0);

    ca0 = na0; ca1 = na1; ca2 = na2; ca3 = na3;
  }

  if (lane < 16) {
    pm[sp * NROWS + row0 + lane] = m;
    pl[sp * NROWS + row0 + lane] = lrow;
  }
#pragma unroll
  for (int nt = 0; nt < 4; nt++)
#pragma unroll
    for (int q2 = 0; q2 < 4; q2++)
      pacc[((size_t)sp * NROWS + row0 + 4 * g + q2) * 64 + nt * 16 + r] = acc[nt][q2];
}

// ---------------------------------------------------------------------------
// Kernel C: combine split partials. One thread per output element. (exp2 domain)
// ---------------------------------------------------------------------------
__global__ __launch_bounds__(256) void k_comb(
    const float* __restrict__ pm, const float* __restrict__ pl,
    const float* __restrict__ pacc, float* __restrict__ out) {
  int t = blockIdx.x * 256 + threadIdx.x;
  int row = t >> 6, f = t & 63;
  float mv[NSPLIT];
  float M = -INFINITY;
#pragma unroll
  for (int s2 = 0; s2 < NSPLIT; s2++) {
    mv[s2] = pm[s2 * NROWS + row];
    M = fmaxf(M, mv[s2]);
  }
  float L = 0.f, o = 0.f;
#pragma unroll
  for (int s2 = 0; s2 < NSPLIT; s2++) {
    float w = exp2f(mv[s2] - M);
    L += pl[s2 * NROWS + row] * w;
    o += pacc[((size_t)s2 * NROWS + row) * 64 + f] * w;
  }
  out[t] = o / L;
}

extern "C" void kernel_launch(void* const* d_in, const int* in_sizes, int n_in,
                              void* d_out, int out_size, void* d_ws, size_t ws_size,
                              hipStream_t stream) {
  const float* h = (const float*)d_in[0];
  const float* W = (const float*)d_in[1];
  const float* a = (const float*)d_in[2];
  const int* adj = (const int*)d_in[3];
  float* out = (float*)d_out;

  char* ws = (char*)d_ws;
  unsigned short* WhB = (unsigned short*)ws;                     // 1 MB
  float* src = (float*)(ws + (1 << 20));                         // 32 KB
  float* dst = (float*)(ws + (1 << 20) + 32768);                 // 32 KB
  float* pm = (float*)(ws + (1 << 20) + 65536);                  // 256 KB
  float* pl = (float*)(ws + (1 << 20) + 65536 + NSPLIT * NROWS * 4);
  float* pacc = (float*)(ws + (1 << 20) + 65536 + 2 * NSPLIT * NROWS * 4);  // 16 MB

  hipLaunchKernelGGL(k_prep, dim3(NROWS / 4), dim3(256), 0, stream, h, W, a, WhB, src, dst);
  hipLaunchKernelGGL(k_attn, dim3(512 * NSPLIT / 4), dim3(256), 0, stream,
                     adj, WhB, src, dst, pm, pl, pacc);
  hipLaunchKernelGGL(k_comb, dim3(NROWS * 64 / 256), dim3(256), 0, stream, pm, pl, pacc, out);
}